// Round 1
// baseline (357.729 us; speedup 1.0000x reference)
//
#include <hip/hip_runtime.h>
#include <stdint.h>
#include <stddef.h>

// Problem constants (B=4, L=1024, D=768, H=6, DH=128)
#define BB 4
#define LL 1024
#define DD 768
#define HH 6
#define DHH 128
#define EPS 1e-5f

// Inputs fp32, outputs fp32.
// Output layout (fp32 elements, concatenated in return order):
//   co : (B,H,L,L) = 25165824
//   w  : (B,L,1)   = 4096
//   Vh : (B,H,L,DH)= 3145728
#define CO_ELEMS 25165824
#define W_ELEMS  4096

// ws layout (fp32 elements), ~6.6 MB. All deterministic writes, no atomics.
#define OFF_Q2  0           // 24576
#define OFF_K2  24576       // 24576
#define OFF_WC  49152       // 24576  final col sums
#define OFF_SP  73728       // 6144   per-block (sum,sumsq) BN1 partials
#define OFF_AC  79872       // 16     a1[0..7], c1[8..15]
#define OFF_SS  79888       // 192    BN2 (sum,sumsq) block partials
#define OFF_WP  81920       // 64*24*1024 = 1572864 col-sum strip partials
// total 1654784 floats = 6.62 MB

typedef __attribute__((ext_vector_type(8))) short short8;
typedef __attribute__((ext_vector_type(4))) float f32x4;

// load 8 contiguous fp32, truncate to bf16 fragment
__device__ __forceinline__ short8 ld_bf8(const float* __restrict__ p) {
    const float4 a = *(const float4*)(p);
    const float4 b = *(const float4*)(p + 4);
    short8 r;
    r[0] = (short)(__float_as_uint(a.x) >> 16);
    r[1] = (short)(__float_as_uint(a.y) >> 16);
    r[2] = (short)(__float_as_uint(a.z) >> 16);
    r[3] = (short)(__float_as_uint(a.w) >> 16);
    r[4] = (short)(__float_as_uint(b.x) >> 16);
    r[5] = (short)(__float_as_uint(b.y) >> 16);
    r[6] = (short)(__float_as_uint(b.z) >> 16);
    r[7] = (short)(__float_as_uint(b.w) >> 16);
    return r;
}

// ------------------------------------------------- q2 / k2 (row sq-norms)
__global__ void k_rownorm(const float* __restrict__ Q,
                          const float* __restrict__ K,
                          float* __restrict__ ws) {
    int gid = blockIdx.x * 256 + threadIdx.x;       // 196608
    int sub = gid & 3;
    int rg  = gid >> 2;
    int which = (rg >= 24576);
    int rid = which ? rg - 24576 : rg;              // bh*1024 + i
    int bh = rid >> 10, i = rid & 1023;
    int b = bh / HH, h = bh - b * HH;
    const float* src = (which ? K : Q) + (size_t)(b * LL + i) * DD + h * DHH;
    float s = 0.f;
#pragma unroll
    for (int kk = 0; kk < 8; kk++) {
        float4 v = *(const float4*)(src + (sub + 4 * kk) * 4);
        s += v.x * v.x + v.y * v.y + v.z * v.z + v.w * v.w;
    }
    s += __shfl_xor(s, 1);
    s += __shfl_xor(s, 2);
    if (sub == 0) ws[(which ? OFF_K2 : OFF_Q2) + rid] = s;
}

// ------------------------------------------------- Vh output (exact copy)
__global__ void k_vh(const float* __restrict__ V, float* __restrict__ out) {
    int cid = blockIdx.x * 256 + threadIdx.x;       // 786432 float4 chunks
    if (cid >= 786432) return;
    int d4 = cid & 31;
    int rest = cid >> 5;
    int l = rest & 1023;
    int bh = rest >> 10;
    int b = bh / HH, h = bh - b * HH;
    f32x4 v = *(const f32x4*)(V + (size_t)(b * LL + l) * DD + h * DHH + d4 * 4);
    __builtin_nontemporal_store(v, (f32x4*)(out + (size_t)cid * 4));
}

// ---- pass 1: STATS ONLY. Same MFMA/S arithmetic as before (bit-identical
// BN1 stats), but the raw-S store to co is deleted — S is recomputed in the
// fused pass 2, eliminating 100MB write + 100MB read of HBM round-trip.
__global__ __launch_bounds__(256) void k_gemm_stats(
        const float* __restrict__ Q, const float* __restrict__ Km,
        const float* __restrict__ q2, const float* __restrict__ k2,
        float* __restrict__ statsP) {
    const int bh = blockIdx.z, b = bh / HH, h = bh - b * HH;
    const int tid = threadIdx.x, lane = tid & 63, wave = tid >> 6;
    const int wr = wave >> 1, wc = wave & 1;
    const int ibase = blockIdx.y * 64 + wr * 32;
    const int jbase = blockIdx.x * 128 + wc * 64;
    const int lm = lane & 15, quad = lane >> 4;
    const float* Qb = Q + (size_t)b * LL * DD + h * DHH;
    const float* Kb = Km + (size_t)b * LL * DD + h * DHH;

    f32x4 acc[2][4];
#pragma unroll
    for (int ti = 0; ti < 2; ti++)
#pragma unroll
        for (int tj = 0; tj < 4; tj++) acc[ti][tj] = (f32x4)(0.0f);

#pragma unroll
    for (int kk = 0; kk < 4; kk++) {
        const int d0 = kk * 32 + quad * 8;
        short8 af[2], bfr[4];
        af[0] = ld_bf8(Qb + (size_t)(ibase + lm) * DD + d0);
        af[1] = ld_bf8(Qb + (size_t)(ibase + 16 + lm) * DD + d0);
#pragma unroll
        for (int tj = 0; tj < 4; tj++)
            bfr[tj] = ld_bf8(Kb + (size_t)(jbase + tj * 16 + lm) * DD + d0);
#pragma unroll
        for (int ti = 0; ti < 2; ti++)
#pragma unroll
            for (int tj = 0; tj < 4; tj++)
                acc[ti][tj] = __builtin_amdgcn_mfma_f32_16x16x32_bf16(af[ti], bfr[tj], acc[ti][tj], 0, 0, 0);
    }

    float q2v[2][4], k2v[4];
#pragma unroll
    for (int ti = 0; ti < 2; ti++)
#pragma unroll
        for (int r = 0; r < 4; r++)
            q2v[ti][r] = q2[bh * 1024 + ibase + ti * 16 + quad * 4 + r];
#pragma unroll
    for (int tj = 0; tj < 4; tj++)
        k2v[tj] = k2[bh * 1024 + jbase + tj * 16 + lm];

    float s = 0.f, s2 = 0.f;
#pragma unroll
    for (int ti = 0; ti < 2; ti++)
#pragma unroll
        for (int tj = 0; tj < 4; tj++)
#pragma unroll
            for (int r = 0; r < 4; r++) {
                float S = 2.0f * acc[ti][tj][r] - q2v[ti][r] - k2v[tj];
                s += S; s2 += S * S;
            }

    __shared__ float rA[256], rB[256];
    rA[tid] = s; rB[tid] = s2;
    __syncthreads();
    for (int off = 128; off > 0; off >>= 1) {
        if (tid < off) { rA[tid] += rA[tid + off]; rB[tid] += rB[tid + off]; }
        __syncthreads();
    }
    if (tid == 0) {
        int blk = blockIdx.y * 8 + blockIdx.x;         // 0..127
        int base = (bh * 128 + blk) * 2;
        statsP[base] = rA[0];
        statsP[base + 1] = rB[0];
    }
}

// --------------------------------------------- reduce BN1 stats -> ac
__global__ void k_stats(const float* __restrict__ statsP,
                        const float* __restrict__ g1, const float* __restrict__ b1,
                        float* __restrict__ ac) {
    __shared__ float rA[256], rB[256];
    const int t = threadIdx.x;
    for (int h = 0; h < HH; h++) {
        float s = 0.f, s2 = 0.f;
        for (int m = t; m < 512; m += 256) {           // 4 batches * 128 blocks
            int b = m >> 7, blk = m & 127;
            int base = ((b * HH + h) * 128 + blk) * 2;
            s += statsP[base]; s2 += statsP[base + 1];
        }
        rA[t] = s; rB[t] = s2;
        __syncthreads();
        for (int off = 128; off > 0; off >>= 1) {
            if (t < off) { rA[t] += rA[t + off]; rB[t] += rB[t + off]; }
            __syncthreads();
        }
        if (t == 0) {
            const float N = 4194304.f;                 // 4*1024*1024
            float m_ = rA[0] / N;
            float var = fmaxf(rB[0] / N - m_ * m_, 0.0f);
            float r = rsqrtf(var + EPS);
            float a = r * g1[h];
            ac[h] = a;
            ac[8 + h] = b1[h] - m_ * a;
        }
        __syncthreads();
    }
}

// ---- pass 2 (FUSED): recompute S via MFMA (bit-identical kk-chain to
// pass 1), BN+mask+exp, in-register row-softmax, coalesced f32x4
// nontemporal p-write, deterministic col-sum strip partials.
// Operand-swapped MFMA: mfma(K_frag, Q_frag) -> acc[r] holds
// (j = jb+quad*4+r, i = i0+lm): each lane owns ONE row x 4 CONSECUTIVE
// cols per j-tile => f32x4 stores, scalar per-lane rowsum.
// blockIdx.x = bh so all strips of one bh land on XCD bh%8 (24%8==0):
// K/Q slabs (0.5MB each) stay L2-resident per XCD.
__global__ __launch_bounds__(512) void k_fused(
        const float* __restrict__ Q, const float* __restrict__ Km,
        const float* __restrict__ q2, const float* __restrict__ k2,
        const float* __restrict__ ac, const unsigned char* __restrict__ bx,
        float* __restrict__ co, float* __restrict__ wcolP) {
    const int bh = blockIdx.x;            // 24
    const int strip = blockIdx.y;         // 64 strips of 16 rows
    const int b = bh / HH, h = bh - b * HH;
    const int t = threadIdx.x, lane = t & 63, w = t >> 6;   // 8 waves
    const int lm = lane & 15, quad = lane >> 4;
    const int i0 = strip * 16;
    const int jw = w * 128;               // wave's 128-col range
    const float* Qb = Q + (size_t)b * LL * DD + h * DHH;
    const float* Kb = Km + (size_t)b * LL * DD + h * DHH;
    const float a1 = ac[h], c1 = ac[8 + h];
    const unsigned char* bxb = bx + b * LL;

    // Q fragments (B-operand): rows i0+lm (16 rows), k-chunks by quad
    short8 qf[4];
#pragma unroll
    for (int kk = 0; kk < 4; kk++)
        qf[kk] = ld_bf8(Qb + (size_t)(i0 + lm) * DD + kk * 32 + quad * 8);

    const bool vi = (bxb[i0 + lm] == 0);
    const float q2v = q2[bh * 1024 + i0 + lm];

    f32x4 e[8];
    float rsum = 0.f;
#pragma unroll
    for (int jt = 0; jt < 8; jt++) {
        const int jb = jw + jt * 16;
        short8 kf[4];
#pragma unroll
        for (int kk = 0; kk < 4; kk++)
            kf[kk] = ld_bf8(Kb + (size_t)(jb + lm) * DD + kk * 32 + quad * 8);
        f32x4 acc = (f32x4)(0.0f);
#pragma unroll
        for (int kk = 0; kk < 4; kk++)
            acc = __builtin_amdgcn_mfma_f32_16x16x32_bf16(kf[kk], qf[kk], acc, 0, 0, 0);
        // acc[r]: j = jb + quad*4 + r, i = i0 + lm
        const f32x4 k2v = *(const f32x4*)(k2 + bh * 1024 + jb + quad * 4);
        const uchar4 m4 = *(const uchar4*)(bxb + jb + quad * 4);
        f32x4 ev;
        ev[0] = (vi && m4.x == 0) ? __expf(fminf(a1 * (2.0f * acc[0] - q2v - k2v[0]) + c1, 60.0f)) : 1.0f;
        ev[1] = (vi && m4.y == 0) ? __expf(fminf(a1 * (2.0f * acc[1] - q2v - k2v[1]) + c1, 60.0f)) : 1.0f;
        ev[2] = (vi && m4.z == 0) ? __expf(fminf(a1 * (2.0f * acc[2] - q2v - k2v[2]) + c1, 60.0f)) : 1.0f;
        ev[3] = (vi && m4.w == 0) ? __expf(fminf(a1 * (2.0f * acc[3] - q2v - k2v[3]) + c1, 60.0f)) : 1.0f;
        e[jt] = ev;
        rsum += (ev[0] + ev[1]) + (ev[2] + ev[3]);
    }
    // row-sum: reduce over quads (j-chunks within wave), then across waves
    rsum += __shfl_xor(rsum, 16);
    rsum += __shfl_xor(rsum, 32);
    __shared__ float rs[8][16];
    __shared__ float invs[16];
    if (quad == 0) rs[w][lm] = rsum;
    __syncthreads();
    if (t < 16) {
        float s = 0.f;
#pragma unroll
        for (int ww = 0; ww < 8; ww++) s += rs[ww][t];
        invs[t] = 1.0f / s;
    }
    __syncthreads();
    const float inv = invs[lm];

    float* rowbase = co + ((size_t)bh << 20) + (size_t)(i0 + lm) * 1024 + jw;
    float* wp = wcolP + ((size_t)strip * 24 + bh) * 1024 + jw;
#pragma unroll
    for (int jt = 0; jt < 8; jt++) {
        f32x4 p = e[jt];
        p[0] *= inv; p[1] *= inv; p[2] *= inv; p[3] *= inv;
        __builtin_nontemporal_store(p, (f32x4*)(rowbase + jt * 16 + quad * 4));
        // col-sum over the strip's 16 rows (lanes differing in lm)
        f32x4 cs = p;
#pragma unroll
        for (int m = 1; m < 16; m <<= 1) {
            cs[0] += __shfl_xor(cs[0], m);
            cs[1] += __shfl_xor(cs[1], m);
            cs[2] += __shfl_xor(cs[2], m);
            cs[3] += __shfl_xor(cs[3], m);
        }
        if (lm == 0) *(f32x4*)(wp + jt * 16 + quad * 4) = cs;
    }
}

// ---- reduce col-sum strip partials -> wcol; fused BN2 block partials
__global__ void k_wcol_reduce(const float* __restrict__ wcolP,
                              float* __restrict__ wcol, float* __restrict__ ws2) {
    const int t = threadIdx.x;
    int g = blockIdx.x * 256 + t;                    // 24576
    float s = 0.f;
#pragma unroll 8
    for (int strip = 0; strip < 64; strip++)
        s += wcolP[(size_t)strip * 24576 + g];
    wcol[g] = s;
    float a = s, b = s * s;
#pragma unroll
    for (int off = 1; off < 64; off <<= 1) { a += __shfl_xor(a, off); b += __shfl_xor(b, off); }
    __shared__ float sc[4][2];
    if ((t & 63) == 0) { sc[t >> 6][0] = a; sc[t >> 6][1] = b; }
    __syncthreads();
    if (t == 0) {
        ws2[blockIdx.x * 2]     = sc[0][0] + sc[1][0] + sc[2][0] + sc[3][0];
        ws2[blockIdx.x * 2 + 1] = sc[0][1] + sc[1][1] + sc[2][1] + sc[3][1];
    }
}

// ------- tail: BN2 (from block partials) + gate + per-batch softmax
__global__ __launch_bounds__(1024) void k_tail(
        const float* __restrict__ wcol, const float* __restrict__ ws2,
        const unsigned char* __restrict__ bx,
        const float* __restrict__ g2, const float* __restrict__ b2,
        const float* __restrict__ Wp, const float* __restrict__ bp,
        float* __restrict__ wout) {
    const int t = threadIdx.x, lane = t & 63, wv = t >> 6;
    __shared__ float abuf[12];       // a2s[0..5], c2s[6..11]
    __shared__ float xb[4096];
    __shared__ float wred[16][2];

    if (t < HH) {
        float s = 0.f, s2 = 0.f;
        for (int b = 0; b < 4; b++) {
            int bh = b * HH + t;
#pragma unroll
            for (int sub = 0; sub < 4; sub++) {
                int blk = bh * 4 + sub;
                s += ws2[blk * 2];
                s2 += ws2[blk * 2 + 1];
            }
        }
        float m = s / 4096.f;
        float var = fmaxf(s2 / 4096.f - m * m, 0.0f);
        float r = rsqrtf(var + EPS);
        float a = r * g2[t];
        abuf[t] = a;
        abuf[6 + t] = b2[t] - m * a;
    }
    __syncthreads();

    const float bp0 = bp[0], bp1 = bp[1];
#pragma unroll
    for (int p = 0; p < 4; p++) {
        int idx = t + p * 1024;
        int b = idx >> 10, l = idx & 1023;
        float z0 = bp0, z1 = bp1;
#pragma unroll
        for (int h = 0; h < HH; h++) {
            float wn = abuf[h] * wcol[(size_t)(b * HH + h) * 1024 + l] + abuf[6 + h];
            z0 += wn * Wp[h];
            z1 += wn * Wp[HH + h];
        }
        float pc = 1.0f / (1.0f + __expf(z1 - z0));
        xb[idx] = bx[b * LL + l] ? -INFINITY : pc;
    }
    __syncthreads();

    const int bb = t >> 8, tb = t & 255;
    float4 xv = *(const float4*)&xb[bb * 1024 + tb * 4];
    float mx = fmaxf(fmaxf(xv.x, xv.y), fmaxf(xv.z, xv.w));
#pragma unroll
    for (int off = 1; off < 64; off <<= 1) mx = fmaxf(mx, __shfl_xor(mx, off));
    if (lane == 0) wred[wv][0] = mx;
    __syncthreads();
    mx = fmaxf(fmaxf(wred[bb * 4][0], wred[bb * 4 + 1][0]),
               fmaxf(wred[bb * 4 + 2][0], wred[bb * 4 + 3][0]));
    float e0 = __expf(xv.x - mx), e1 = __expf(xv.y - mx);
    float e2 = __expf(xv.z - mx), e3 = __expf(xv.w - mx);
    float ss = e0 + e1 + e2 + e3;
#pragma unroll
    for (int off = 1; off < 64; off <<= 1) ss += __shfl_xor(ss, off);
    if (lane == 0) wred[wv][1] = ss;
    __syncthreads();
    float sum = wred[bb * 4][1] + wred[bb * 4 + 1][1] + wred[bb * 4 + 2][1] + wred[bb * 4 + 3][1];
    float4 o;
    o.x = e0 / sum; o.y = e1 / sum; o.z = e2 / sum; o.w = e3 / sum;
    *(float4*)&wout[bb * 1024 + tb * 4] = o;
}

extern "C" void kernel_launch(void* const* d_in, const int* in_sizes, int n_in,
                              void* d_out, int out_size, void* d_ws, size_t ws_size,
                              hipStream_t stream) {
    const float* Q  = (const float*)d_in[0];
    const float* K  = (const float*)d_in[1];
    const float* V  = (const float*)d_in[2];
    // d_in[3] = pad_mask — derivable from bx_packed, unused
    const unsigned char* bx = (const unsigned char*)d_in[4];
    const float* g1 = (const float*)d_in[5];
    const float* b1 = (const float*)d_in[6];
    const float* g2 = (const float*)d_in[7];
    const float* b2 = (const float*)d_in[8];
    const float* Wp = (const float*)d_in[9];
    const float* bp = (const float*)d_in[10];

    float* out  = (float*)d_out;
    float* co   = out;                        // (B,H,L,L)
    float* wout = out + CO_ELEMS;             // (B,L,1)
    float* vh   = out + CO_ELEMS + W_ELEMS;   // (B,H,L,DH)

    float* ws = (float*)d_ws;                 // ~6.6 MB
    float* q2     = ws + OFF_Q2;
    float* k2     = ws + OFF_K2;
    float* wcol   = ws + OFF_WC;
    float* statsP = ws + OFF_SP;
    float* ac     = ws + OFF_AC;
    float* ws2    = ws + OFF_SS;
    float* wcolP  = ws + OFF_WP;

    k_rownorm<<<768, 256, 0, stream>>>(Q, K, ws);
    k_vh<<<3072, 256, 0, stream>>>(V, vh);
    k_gemm_stats<<<dim3(8, 16, BB * HH), 256, 0, stream>>>(Q, K, q2, k2, statsP);
    k_stats<<<1, 256, 0, stream>>>(statsP, g1, b1, ac);
    k_fused<<<dim3(24, 64), 512, 0, stream>>>(Q, K, q2, k2, ac, bx, co, wcolP);
    k_wcol_reduce<<<96, 256, 0, stream>>>(wcolP, wcol, ws2);
    k_tail<<<1, 1024, 0, stream>>>(wcol, ws2, bx, g2, b2, Wp, bp, wout);
}